// Round 7
// baseline (1601221.191 us; speedup 1.0000x reference)
//
#include <hip/hip_runtime.h>
#include <hip/hip_bf16.h>

// MogLSTM S=512, B=64, E=H=1024. Batch-split across XCDs: 8 batch rows per
// XCD-group of 32 blocks (roster via HW_REG_XCC_ID; 1 block/CU forced by
// 100KB LDS). Cross-block traffic in-group L2 only: plain stores, sc0 loads,
// L2-local atomic barriers. R4: barrier targets x32. R5: 3-band handoff.
// R6 lesson: error is dominated by FIXED bf16 perturbation of weights (the
// recurrence amplifies a changed map; per-step random noise averages out).
// R7: weights effectively exact -- W streamed as f32 and split on the fly
// (bh+bl, 3 MFMAs), Q/R stored as bf16 hi+lo pairs (unconditional).

using bf16   = __bf16;
using bf16x8 = __attribute__((ext_vector_type(8))) __bf16;
using f32x4  = __attribute__((ext_vector_type(4))) float;
using u32    = unsigned int;

#define S_LEN 512
#define XHS   6144  // bands: x_hi|x_lo|hw_hi|hw_lo|hn_hi|hn_lo (1024 each)
#define MFMA16(a,b,c) __builtin_amdgcn_mfma_f32_16x16x32_bf16((a),(b),(c),0,0,0)

__device__ __forceinline__ float fsig(float x)  { return 1.f/(1.f+__expf(-x)); }
__device__ __forceinline__ float ftanh(float x) { return 1.f - 2.f/(1.f+__expf(2.f*x)); }

#define ALOAD(dst, p, OFF) \
  asm volatile("global_load_dwordx4 %0, %1, off offset:" OFF " sc0" \
               : "=v"(dst) : "v"(p) : "memory")

#define ALOAD16(arr, p) do { \
  ALOAD(arr[0],(p),"0");   ALOAD(arr[1],(p),"64");  ALOAD(arr[2],(p),"128"); \
  ALOAD(arr[3],(p),"192"); ALOAD(arr[4],(p),"256"); ALOAD(arr[5],(p),"320"); \
  ALOAD(arr[6],(p),"384"); ALOAD(arr[7],(p),"448"); ALOAD(arr[8],(p),"512"); \
  ALOAD(arr[9],(p),"576"); ALOAD(arr[10],(p),"640");ALOAD(arr[11],(p),"704"); \
  ALOAD(arr[12],(p),"768");ALOAD(arr[13],(p),"832");ALOAD(arr[14],(p),"896"); \
  ALOAD(arr[15],(p),"960"); \
  asm volatile("s_waitcnt vmcnt(0)" ::: "memory"); \
  __builtin_amdgcn_sched_barrier(0); \
} while (0)

#define ALOAD8(arr, p) do { \
  ALOAD(arr[0],(p),"0");   ALOAD(arr[1],(p),"64");  ALOAD(arr[2],(p),"128"); \
  ALOAD(arr[3],(p),"192"); ALOAD(arr[4],(p),"256"); ALOAD(arr[5],(p),"320"); \
  ALOAD(arr[6],(p),"384"); ALOAD(arr[7],(p),"448"); \
  asm volatile("s_waitcnt vmcnt(0)" ::: "memory"); \
  __builtin_amdgcn_sched_barrier(0); \
} while (0)

__device__ __forceinline__ void asth(unsigned short* p, u32 v) {
  asm volatile("global_store_short %0, %1, off sc0 sc1" :: "v"(p), "v"(v) : "memory");
}
// split store: hi at p, lo residual at p+1024 (elements)
__device__ __forceinline__ void sstore(unsigned short* p, float v) {
  bf16 hi = (bf16)v;
  float rem = v - (float)hi;
  bf16 lo = (bf16)rem;
  asth(p, (u32)__builtin_bit_cast(unsigned short, hi));
  asth(p + 1024, (u32)__builtin_bit_cast(unsigned short, lo));
}

// group-local barrier (one XCD/L2). Poll cap + abort flag => no hangs.
__device__ __forceinline__ void gbar(u32* ctr, u32 target, u32* abortf) {
  asm volatile("s_waitcnt vmcnt(0)" ::: "memory");
  __syncthreads();
  if (threadIdx.x == 0) {
    asm volatile("global_atomic_add %0, %1, off" :: "v"(ctr), "v"(1u) : "memory");
    u32 v = 0; int it = 0;
    for (;;) {
      asm volatile("global_load_dword %0, %1, off sc0\n\ts_waitcnt vmcnt(0)"
                   : "=v"(v) : "v"(ctr) : "memory");
      if (v >= target) break;
      if (++it > (1 << 17)) {
        __hip_atomic_store(abortf, 1u, __ATOMIC_RELAXED, __HIP_MEMORY_SCOPE_AGENT);
        break;
      }
      if ((it & 4095) == 0 &&
          __hip_atomic_load(abortf, __ATOMIC_RELAXED, __HIP_MEMORY_SCOPE_AGENT))
        break;
      __builtin_amdgcn_s_sleep(1);
    }
  }
  __syncthreads();
}

// mog GEMM: split-A (lo at ah_p+1024 elems) x split-B (hi/lo arrays).
__device__ __forceinline__ f32x4 mog_gemm3(const bf16* ah_p, const bf16* bh_p,
                                           const bf16* bl_p) {
  bf16x8 ah[16], al[16];
  ALOAD16(ah, ah_p);
  ALOAD16(al, ah_p + 1024);
  f32x4 acc = {0.f, 0.f, 0.f, 0.f};
#pragma unroll
  for (int s = 0; s < 16; ++s) {
    bf16x8 bh = *(const bf16x8*)(bh_p + s * 32);
    bf16x8 bl = *(const bf16x8*)(bl_p + s * 32);
    acc = MFMA16(al[s], bh, acc);
    acc = MFMA16(ah[s], bl, acc);
    acc = MFMA16(ah[s], bh, acc);
  }
  return acc;
}

// ---------------- prologue: Q/R hi+lo, zero activations/barriers ----------
__global__ void cvt_init(const float* __restrict__ Q, const float* __restrict__ R,
                         bf16* __restrict__ Qb, bf16* __restrict__ Rb,
                         bf16* __restrict__ Qlo, bf16* __restrict__ Rlo,
                         bf16* __restrict__ xhB, u32* __restrict__ bars) {
  const long tid = (long)blockIdx.x * blockDim.x + threadIdx.x;
  const long nth = (long)gridDim.x * blockDim.x;
  for (long i = tid; i < (long)1024 * 1024 / 4; i += nth) {
    float4 v = ((const float4*)Q)[i];
    bf16 h0 = (bf16)v.x, h1 = (bf16)v.y, h2 = (bf16)v.z, h3 = (bf16)v.w;
    bf16* d = Qb + i * 4; d[0] = h0; d[1] = h1; d[2] = h2; d[3] = h3;
    bf16* dl = Qlo + i * 4;
    dl[0] = (bf16)(v.x - (float)h0); dl[1] = (bf16)(v.y - (float)h1);
    dl[2] = (bf16)(v.z - (float)h2); dl[3] = (bf16)(v.w - (float)h3);
    float4 u = ((const float4*)R)[i];
    bf16 g0 = (bf16)u.x, g1 = (bf16)u.y, g2 = (bf16)u.z, g3 = (bf16)u.w;
    bf16* e = Rb + i * 4; e[0] = g0; e[1] = g1; e[2] = g2; e[3] = g3;
    bf16* el = Rlo + i * 4;
    el[0] = (bf16)(u.x - (float)g0); el[1] = (bf16)(u.y - (float)g1);
    el[2] = (bf16)(u.z - (float)g2); el[3] = (bf16)(u.w - (float)g3);
  }
  for (long i = tid; i < (long)8 * 16 * XHS / 8; i += nth) {
    float4 z; z.x = 0.f; z.y = 0.f; z.z = 0.f; z.w = 0.f;
    ((float4*)xhB)[i] = z;
  }
  if (tid < 2048) bars[tid] = 0u;
}

// ---------------- persistent kernel ----------------
__global__ __launch_bounds__(256, 1) void mog3(
    const float* __restrict__ xin, const float* __restrict__ ball,
    const float* __restrict__ Wf, const bf16* __restrict__ Qb,
    const bf16* __restrict__ Rb, const bf16* __restrict__ Qlo,
    const bf16* __restrict__ Rlo, bf16* __restrict__ xhB,
    u32* bars, float* __restrict__ out) {
  __shared__ __align__(16) char smem[100 * 1024];   // 1 block/CU
  f32x4* redv = (f32x4*)smem;                       // 24 KB partials
  float*  hbuf = (float*)(smem + 24576);            // [8][32] h fp32
  float*  xbuf = (float*)(smem + 25600);            // [8][32] x fp32
  int*    shint = (int*)(smem + 26624);

  const int tid = threadIdx.x;
  if (tid == 0) {
    u32 xcc;
    asm volatile("s_getreg_b32 %0, hwreg(HW_REG_XCC_ID)" : "=s"(xcc));
    xcc &= 7u;
    u32 slot = __hip_atomic_fetch_add(bars + 1024 + xcc, 1u,
                                      __ATOMIC_RELAXED, __HIP_MEMORY_SCOPE_AGENT);
    shint[0] = (int)xcc; shint[1] = (int)slot;
  }
  __syncthreads();
  const int g = shint[0], j = shint[1];
  if (j >= 32) {
    if (tid == 0)
      __hip_atomic_store(bars + 1040, 1u, __ATOMIC_RELAXED, __HIP_MEMORY_SCOPE_AGENT);
    return;
  }

  const int l = tid & 63, w = tid >> 6;
  const int ch = w >> 1, kh = w & 1;
  const int lrow = l & 15;
  const int koff = (l >> 4) * 8;

  u32* ctr    = bars + g * 32;
  u32* abortf = bars + 1040;
  bf16* xh = xhB + (size_t)g * 16 * XHS;
  unsigned short* xh_s = (unsigned short*)xh;

  for (int i = tid; i < 256; i += 256) { hbuf[i] = 0.f; xbuf[i] = 0.f; }
  __syncthreads();

  float breg[2][4], creg[2][4];
#pragma unroll
  for (int hl = 0; hl < 2; ++hl)
#pragma unroll
    for (int q = 0; q < 4; ++q) creg[hl][q] = 0.f;
  if (w == 0 && l < 32) {
#pragma unroll
    for (int hl = 0; hl < 2; ++hl)
#pragma unroll
      for (int gi = 0; gi < 4; ++gi)
        breg[hl][gi] = ball[gi * 1024 + 32 * j + hl * 16 + lrow];
  }

  const size_t mog_brow = (size_t)(32 * j + ch * 16 + lrow) * 1024 + kh * 512 + koff;
  const bf16* apx  = xh + (size_t)lrow * XHS + kh * 512 + koff;   // x_hi band
  const bf16* aph  = apx + 2048;                                  // hw_hi band
  const bf16* aph2 = apx + 4096;                                  // hn_hi band

  for (int t = 0; t < S_LEN; ++t) {
    const size_t tb = (size_t)t * 65536;
    const u32 t6 = 6u * (u32)t;

    // ---- P1: x1 = 2*sig(h_new @ Q^T) * x_t    (reads hn, writes x)
    {
      f32x4 acc = mog_gemm3(aph2, Qb + mog_brow, Qlo + mog_brow);
      if (kh == 1) redv[ch * 64 + l] = acc;
      __syncthreads();
      if (kh == 0) {
        acc += redv[ch * 64 + l];
        if (l < 32) {
          const int lc = ch * 16 + lrow, gc = 32 * j + lc;
#pragma unroll
          for (int q = 0; q < 4; ++q) {
            const int row = (l >> 4) * 4 + q;
            float xt = xin[tb + (size_t)(8 * g + row) * 1024 + gc];
            float nv = 2.f * fsig(acc[q]) * xt;
            xbuf[row * 32 + lc] = nv;
            sstore(xh_s + (size_t)row * XHS + gc, nv);
          }
        }
      }
      gbar(ctr, 32u * (t6 + 1), abortf);
    }
    // ---- P2: h2 = 2*sig(x1 @ R^T) * h         (reads x, writes hw)
    {
      f32x4 acc = mog_gemm3(apx, Rb + mog_brow, Rlo + mog_brow);
      if (kh == 1) redv[ch * 64 + l] = acc;
      __syncthreads();
      if (kh == 0) {
        acc += redv[ch * 64 + l];
        if (l < 32) {
          const int lc = ch * 16 + lrow, gc = 32 * j + lc;
#pragma unroll
          for (int q = 0; q < 4; ++q) {
            const int row = (l >> 4) * 4 + q;
            float nv = 2.f * fsig(acc[q]) * hbuf[row * 32 + lc];
            hbuf[row * 32 + lc] = nv;
            sstore(xh_s + (size_t)row * XHS + 2048 + gc, nv);
          }
        }
      }
      gbar(ctr, 32u * (t6 + 2), abortf);
    }
    // ---- P3: x3 = 2*sig(h2 @ Q^T) * x1        (reads hw, writes x)
    {
      f32x4 acc = mog_gemm3(aph, Qb + mog_brow, Qlo + mog_brow);
      if (kh == 1) redv[ch * 64 + l] = acc;
      __syncthreads();
      if (kh == 0) {
        acc += redv[ch * 64 + l];
        if (l < 32) {
          const int lc = ch * 16 + lrow, gc = 32 * j + lc;
#pragma unroll
          for (int q = 0; q < 4; ++q) {
            const int row = (l >> 4) * 4 + q;
            float nv = 2.f * fsig(acc[q]) * xbuf[row * 32 + lc];
            xbuf[row * 32 + lc] = nv;
            sstore(xh_s + (size_t)row * XHS + gc, nv);
          }
        }
      }
      gbar(ctr, 32u * (t6 + 3), abortf);
    }
    // ---- P4: h4 = 2*sig(x3 @ R^T) * h2        (reads x, writes hw)
    {
      f32x4 acc = mog_gemm3(apx, Rb + mog_brow, Rlo + mog_brow);
      if (kh == 1) redv[ch * 64 + l] = acc;
      __syncthreads();
      if (kh == 0) {
        acc += redv[ch * 64 + l];
        if (l < 32) {
          const int lc = ch * 16 + lrow, gc = 32 * j + lc;
#pragma unroll
          for (int q = 0; q < 4; ++q) {
            const int row = (l >> 4) * 4 + q;
            float nv = 2.f * fsig(acc[q]) * hbuf[row * 32 + lc];
            hbuf[row * 32 + lc] = nv;
            sstore(xh_s + (size_t)row * XHS + 2048 + gc, nv);
          }
        }
      }
      gbar(ctr, 32u * (t6 + 4), abortf);
    }
    // ---- P5: x5 = 2*sig(h4 @ Q^T) * x3        (reads hw, writes x)
    {
      f32x4 acc = mog_gemm3(aph, Qb + mog_brow, Qlo + mog_brow);
      if (kh == 1) redv[ch * 64 + l] = acc;
      __syncthreads();
      if (kh == 0) {
        acc += redv[ch * 64 + l];
        if (l < 32) {
          const int lc = ch * 16 + lrow, gc = 32 * j + lc;
#pragma unroll
          for (int q = 0; q < 4; ++q) {
            const int row = (l >> 4) * 4 + q;
            float nv = 2.f * fsig(acc[q]) * xbuf[row * 32 + lc];
            sstore(xh_s + (size_t)row * XHS + gc, nv);
          }
        }
      }
      gbar(ctr, 32u * (t6 + 5), abortf);
    }
    // ---- P6: z = [x5,h4] @ W^T + b ; gates    (reads x+hw, writes hn)
    // B = f32 W_all streamed directly, split on the fly: 3 MFMAs/frag.
    {
      const int off_hi = (w < 2) ? (w * 512) : (2048 + (w - 2) * 512);
      const bf16* ap = xh + (size_t)lrow * XHS + off_hi + koff;
      const float* wp[8];
#pragma unroll
      for (int n = 0; n < 8; ++n)
        wp[n] = Wf + (size_t)((n >> 1) * 1024 + 32 * j + (n & 1) * 16 + lrow) * 2048
                   + w * 512 + koff;
      f32x4 acc[8];
#pragma unroll
      for (int n = 0; n < 8; ++n) acc[n] = (f32x4){0.f, 0.f, 0.f, 0.f};
#pragma unroll
      for (int half = 0; half < 2; ++half) {
        bf16x8 ah[8], al[8];
        ALOAD8(ah, ap + half * 256);
        ALOAD8(al, ap + 1024 + half * 256);
#pragma unroll
        for (int s = 0; s < 8; ++s) {
          const int ks = half * 8 + s;
#pragma unroll
          for (int n = 0; n < 8; ++n) {
            f32x4 w0 = __builtin_nontemporal_load((const f32x4*)(wp[n] + ks * 32));
            f32x4 w1 = __builtin_nontemporal_load((const f32x4*)(wp[n] + ks * 32 + 4));
            bf16x8 bh, bl;
#pragma unroll
            for (int e = 0; e < 4; ++e) {
              bf16 h0 = (bf16)w0[e]; bh[e] = h0;     bl[e] = (bf16)(w0[e] - (float)h0);
              bf16 h1 = (bf16)w1[e]; bh[4 + e] = h1; bl[4 + e] = (bf16)(w1[e] - (float)h1);
            }
            acc[n] = MFMA16(al[s], bh, acc[n]);
            acc[n] = MFMA16(ah[s], bl, acc[n]);
            acc[n] = MFMA16(ah[s], bh, acc[n]);
          }
        }
      }
      if (w) {
#pragma unroll
        for (int n = 0; n < 8; ++n) redv[((w - 1) * 8 + n) * 64 + l] = acc[n];
      }
      __syncthreads();
      if (w == 0) {
#pragma unroll
        for (int n = 0; n < 8; ++n) {
#pragma unroll
          for (int kk = 0; kk < 3; ++kk) acc[n] += redv[(kk * 8 + n) * 64 + l];
        }
        if (l < 32) {
#pragma unroll
          for (int hl = 0; hl < 2; ++hl) {
            const int lc = hl * 16 + lrow, gc = 32 * j + lc;
#pragma unroll
            for (int q = 0; q < 4; ++q) {
              const int row = (l >> 4) * 4 + q;
              float zi = acc[0 + hl][q] + breg[hl][0];
              float zf = acc[2 + hl][q] + breg[hl][1];
              float zg = acc[4 + hl][q] + breg[hl][2];
              float zo = acc[6 + hl][q] + breg[hl][3];
              float cc = fsig(zf) * creg[hl][q] + fsig(zi) * ftanh(zg);
              float hh = fsig(zo) * ftanh(cc);
              creg[hl][q] = cc;
              hbuf[row * 32 + lc] = hh;
              sstore(xh_s + (size_t)row * XHS + 4096 + gc, hh);   // hn bands
              out[tb + (size_t)(8 * g + row) * 1024 + gc] = hh;
              if (t == S_LEN - 1) {
                out[(size_t)512 * 65536 + (size_t)(8 * g + row) * 1024 + gc] = hh;
                out[(size_t)512 * 65536 + 65536 + (size_t)(8 * g + row) * 1024 + gc] = cc;
              }
            }
          }
        }
      }
      gbar(ctr, 32u * (t6 + 6), abortf);
    }
  }
}

extern "C" void kernel_launch(void* const* d_in, const int* in_sizes, int n_in,
                              void* d_out, int out_size, void* d_ws, size_t ws_size,
                              hipStream_t stream) {
  (void)in_sizes; (void)n_in; (void)out_size; (void)ws_size;
  const float* x    = (const float*)d_in[0];
  const float* Wall = (const float*)d_in[1];
  const float* ball = (const float*)d_in[2];
  const float* Q    = (const float*)d_in[3];
  const float* R    = (const float*)d_in[4];

  char* ws = (char*)d_ws;
  size_t off = 0;
  bf16* Qb  = (bf16*)(ws + off); off += (size_t)1024 * 1024 * 2;   // 2 MB
  bf16* Rb  = (bf16*)(ws + off); off += (size_t)1024 * 1024 * 2;   // 2 MB
  bf16* Qlo = (bf16*)(ws + off); off += (size_t)1024 * 1024 * 2;   // 2 MB
  bf16* Rlo = (bf16*)(ws + off); off += (size_t)1024 * 1024 * 2;   // 2 MB
  bf16* xhB = (bf16*)(ws + off); off += (size_t)8 * 16 * XHS * 2;  // 1.5 MB
  u32* bars = (u32*)(ws + off);  off += 8192;

  cvt_init<<<1024, 256, 0, stream>>>(Q, R, Qb, Rb, Qlo, Rlo, xhB, bars);
  mog3<<<256, 256, 0, stream>>>(x, ball, Wall, Qb, Rb, Qlo, Rlo, xhB, bars,
                                (float*)d_out);
}

// Round 8
// 68269.977 us; speedup vs baseline: 23.4543x; 23.4543x over previous
//
#include <hip/hip_runtime.h>
#include <hip/hip_bf16.h>
#include <math.h>

// MogLSTM S=512, B=64, E=H=1024. R8 pivot: kernel-per-phase, graph-replayed.
// 6 kernels/step x 512 steps; kernel boundaries provide device-wide sync
// (no custom barriers, no sc0/sc1 games). Numerics = r7's proven split
// recipe + al*bl term + accurate expf/tanhf: activations and Q/R as bf16
// hi+lo pairs, W split from f32 on the fly, fp32 masters and elementwise.
// Bands X / H(working) / N(h-new) keep each kernel's writes disjoint from
// concurrent readers (r5 lesson: gate writes N, read only by next P1).

using bf16   = __bf16;
using bf16x8 = __attribute__((ext_vector_type(8))) __bf16;
using f32x4  = __attribute__((ext_vector_type(4))) float;

#define MFMA16(a,b,c) __builtin_amdgcn_mfma_f32_16x16x32_bf16((a),(b),(c),0,0,0)

__device__ __forceinline__ float fsig(float x) { return 1.f / (1.f + expf(-x)); }

// ---------------- prologue: Q/R hi+lo split, zero state ----------------
__global__ void prep(const float* __restrict__ Q, const float* __restrict__ R,
                     bf16* __restrict__ Qh, bf16* __restrict__ Ql,
                     bf16* __restrict__ Rh, bf16* __restrict__ Rl,
                     float* __restrict__ hM, float* __restrict__ cM,
                     bf16* __restrict__ Nh, bf16* __restrict__ Nl) {
  const long tid = (long)blockIdx.x * blockDim.x + threadIdx.x;
  const long nth = (long)gridDim.x * blockDim.x;
  for (long i = tid; i < 1024L * 1024 / 4; i += nth) {
    float4 v = ((const float4*)Q)[i];
    bf16 a0 = (bf16)v.x, a1 = (bf16)v.y, a2 = (bf16)v.z, a3 = (bf16)v.w;
    Qh[i*4+0] = a0; Qh[i*4+1] = a1; Qh[i*4+2] = a2; Qh[i*4+3] = a3;
    Ql[i*4+0] = (bf16)(v.x - (float)a0); Ql[i*4+1] = (bf16)(v.y - (float)a1);
    Ql[i*4+2] = (bf16)(v.z - (float)a2); Ql[i*4+3] = (bf16)(v.w - (float)a3);
    float4 u = ((const float4*)R)[i];
    bf16 b0 = (bf16)u.x, b1 = (bf16)u.y, b2 = (bf16)u.z, b3 = (bf16)u.w;
    Rh[i*4+0] = b0; Rh[i*4+1] = b1; Rh[i*4+2] = b2; Rh[i*4+3] = b3;
    Rl[i*4+0] = (bf16)(u.x - (float)b0); Rl[i*4+1] = (bf16)(u.y - (float)b1);
    Rl[i*4+2] = (bf16)(u.z - (float)b2); Rl[i*4+3] = (bf16)(u.w - (float)b3);
  }
  for (long i = tid; i < 64L * 1024; i += nth) {
    hM[i] = 0.f; cM[i] = 0.f; Nh[i] = (bf16)0.f; Nl[i] = (bf16)0.f;
  }
}

// ---------------- mogrifier phase: P = S @ B^T ; dst = 2*sig(P) * mult ----
// Grid 64 WGs x 256 thr. WG c -> cols 16c..16c+15. Wave w -> K slice of 256.
// A (S) and B operands are hi+lo bf16 pairs: 4-term product per fragment.
__global__ __launch_bounds__(256) void mog_phase(
    const bf16* __restrict__ Ah, const bf16* __restrict__ Al,
    const bf16* __restrict__ Bh, const bf16* __restrict__ Bl,
    const float* __restrict__ mult, float* __restrict__ dstM,
    bf16* __restrict__ Dh, bf16* __restrict__ Dl) {
  __shared__ f32x4 red[3][4][64];
  const int c = blockIdx.x;
  const int tid = threadIdx.x, l = tid & 63, w = tid >> 6;
  const int r16 = l & 15, kg = l >> 4;
  const size_t kb = (size_t)w * 256 + kg * 8;
  const bf16* bhp = Bh + (size_t)(16 * c + r16) * 1024 + kb;
  const bf16* blp = Bl + (size_t)(16 * c + r16) * 1024 + kb;
  f32x4 acc[4] = {};
#pragma unroll
  for (int ks = 0; ks < 8; ++ks) {
    bf16x8 bh = *(const bf16x8*)(bhp + ks * 32);
    bf16x8 bl = *(const bf16x8*)(blp + ks * 32);
#pragma unroll
    for (int m = 0; m < 4; ++m) {
      bf16x8 ah = *(const bf16x8*)(Ah + (size_t)(16 * m + r16) * 1024 + kb + ks * 32);
      bf16x8 al = *(const bf16x8*)(Al + (size_t)(16 * m + r16) * 1024 + kb + ks * 32);
      acc[m] = MFMA16(al, bl, acc[m]);   // smallest term first
      acc[m] = MFMA16(al, bh, acc[m]);
      acc[m] = MFMA16(ah, bl, acc[m]);
      acc[m] = MFMA16(ah, bh, acc[m]);
    }
  }
  if (w) {
#pragma unroll
    for (int m = 0; m < 4; ++m) red[w - 1][m][l] = acc[m];
  }
  __syncthreads();
  if (w == 0) {
#pragma unroll
    for (int m = 0; m < 4; ++m)
#pragma unroll
      for (int kk = 0; kk < 3; ++kk) acc[m] += red[kk][m][l];
    const int col = 16 * c + r16;           // C-frag: col = lane&15
#pragma unroll
    for (int m = 0; m < 4; ++m)
#pragma unroll
      for (int q = 0; q < 4; ++q) {
        const int row = 16 * m + kg * 4 + q;  // row = (lane>>4)*4 + reg
        const size_t idx = (size_t)row * 1024 + col;
        float v = 2.f * fsig(acc[m][q]) * mult[idx];
        dstM[idx] = v;
        bf16 hi = (bf16)v;
        Dh[idx] = hi;
        Dl[idx] = (bf16)(v - (float)hi);
      }
  }
}

// ---------------- gate step: z = [x5,h4] @ W^T + b ; LSTM update ----------
// Grid 64 WGs. WG c -> h-cols 16c..16c+15 for ALL 4 gates (64 W rows).
// Wave w -> K slice of 512 (w<2: x half from X bands; w>=2: h half from H).
// W streamed as f32 and split on the fly (r7-proven), 4-term product.
__global__ __launch_bounds__(256) void gate_step(
    const bf16* __restrict__ Xh, const bf16* __restrict__ Xl,
    const bf16* __restrict__ Hh, const bf16* __restrict__ Hl,
    const float* __restrict__ Wf, const float* __restrict__ ball,
    float* __restrict__ cM, float* __restrict__ hM,
    bf16* __restrict__ Nh, bf16* __restrict__ Nl,
    float* __restrict__ out, int t) {
  __shared__ f32x4 red[3][16][64];   // 48 KB
  const int cblk = blockIdx.x;
  const int tid = threadIdx.x, l = tid & 63, w = tid >> 6;
  const int r16 = l & 15, kg = l >> 4;
  const bf16* Abh = (w < 2) ? Xh : Hh;
  const bf16* Abl = (w < 2) ? Xl : Hl;
  const size_t kb = (size_t)(w & 1) * 512 + kg * 8;   // local k within band
  const float* wp[4];
#pragma unroll
  for (int n = 0; n < 4; ++n)
    wp[n] = Wf + (size_t)(n * 1024 + 16 * cblk + r16) * 2048 + (size_t)w * 512 + kg * 8;
  f32x4 acc[4][4] = {};
#pragma unroll
  for (int ks = 0; ks < 16; ++ks) {
    bf16x8 ah[4], al[4];
#pragma unroll
    for (int m = 0; m < 4; ++m) {
      ah[m] = *(const bf16x8*)(Abh + (size_t)(16 * m + r16) * 1024 + kb + ks * 32);
      al[m] = *(const bf16x8*)(Abl + (size_t)(16 * m + r16) * 1024 + kb + ks * 32);
    }
#pragma unroll
    for (int n = 0; n < 4; ++n) {
      f32x4 w0 = *(const f32x4*)(wp[n] + ks * 32);
      f32x4 w1 = *(const f32x4*)(wp[n] + ks * 32 + 4);
      bf16x8 bh, bl;
#pragma unroll
      for (int e = 0; e < 4; ++e) {
        bf16 t0 = (bf16)w0[e]; bh[e] = t0;     bl[e] = (bf16)(w0[e] - (float)t0);
        bf16 t1 = (bf16)w1[e]; bh[4 + e] = t1; bl[4 + e] = (bf16)(w1[e] - (float)t1);
      }
#pragma unroll
      for (int m = 0; m < 4; ++m) {
        acc[m][n] = MFMA16(al[m], bl, acc[m][n]);
        acc[m][n] = MFMA16(al[m], bh, acc[m][n]);
        acc[m][n] = MFMA16(ah[m], bl, acc[m][n]);
        acc[m][n] = MFMA16(ah[m], bh, acc[m][n]);
      }
    }
  }
  if (w) {
#pragma unroll
    for (int m = 0; m < 4; ++m)
#pragma unroll
      for (int n = 0; n < 4; ++n) red[w - 1][m * 4 + n][l] = acc[m][n];
  }
  __syncthreads();
  if (w == 0) {
#pragma unroll
    for (int m = 0; m < 4; ++m)
#pragma unroll
      for (int n = 0; n < 4; ++n)
#pragma unroll
        for (int kk = 0; kk < 3; ++kk) acc[m][n] += red[kk][m * 4 + n][l];
    const int hcol = 16 * cblk + r16;
    const float bi = ball[hcol], bf_ = ball[1024 + hcol];
    const float bg = ball[2048 + hcol], bo = ball[3072 + hcol];
#pragma unroll
    for (int m = 0; m < 4; ++m)
#pragma unroll
      for (int q = 0; q < 4; ++q) {
        const int row = 16 * m + kg * 4 + q;
        const size_t idx = (size_t)row * 1024 + hcol;
        const float zi = acc[m][0][q] + bi;
        const float zf = acc[m][1][q] + bf_;
        const float zg = acc[m][2][q] + bg;
        const float zo = acc[m][3][q] + bo;
        const float cc = fsig(zf) * cM[idx] + fsig(zi) * tanhf(zg);
        const float hh = fsig(zo) * tanhf(cc);
        cM[idx] = cc;
        hM[idx] = hh;
        bf16 hi = (bf16)hh;
        Nh[idx] = hi;
        Nl[idx] = (bf16)(hh - (float)hi);
        out[(size_t)t * 65536 + idx] = hh;
        if (t == 511) {
          out[(size_t)512 * 65536 + idx] = hh;             // final h
          out[(size_t)512 * 65536 + 65536 + idx] = cc;     // final c
        }
      }
  }
}

extern "C" void kernel_launch(void* const* d_in, const int* in_sizes, int n_in,
                              void* d_out, int out_size, void* d_ws, size_t ws_size,
                              hipStream_t stream) {
  (void)in_sizes; (void)n_in; (void)out_size; (void)ws_size;
  const float* x    = (const float*)d_in[0];
  const float* Wall = (const float*)d_in[1];
  const float* ball = (const float*)d_in[2];
  const float* Q    = (const float*)d_in[3];
  const float* R    = (const float*)d_in[4];
  float* out = (float*)d_out;

  char* ws = (char*)d_ws;
  size_t off = 0;
  bf16* Qh = (bf16*)(ws + off); off += (size_t)1024 * 1024 * 2;   // 2 MB
  bf16* Ql = (bf16*)(ws + off); off += (size_t)1024 * 1024 * 2;
  bf16* Rh = (bf16*)(ws + off); off += (size_t)1024 * 1024 * 2;
  bf16* Rl = (bf16*)(ws + off); off += (size_t)1024 * 1024 * 2;
  bf16* Xh = (bf16*)(ws + off); off += (size_t)64 * 1024 * 2;     // 128 KB each
  bf16* Xl = (bf16*)(ws + off); off += (size_t)64 * 1024 * 2;
  bf16* Hh = (bf16*)(ws + off); off += (size_t)64 * 1024 * 2;
  bf16* Hl = (bf16*)(ws + off); off += (size_t)64 * 1024 * 2;
  bf16* Nh = (bf16*)(ws + off); off += (size_t)64 * 1024 * 2;
  bf16* Nl = (bf16*)(ws + off); off += (size_t)64 * 1024 * 2;
  float* xM = (float*)(ws + off); off += (size_t)64 * 1024 * 4;   // 256 KB each
  float* hM = (float*)(ws + off); off += (size_t)64 * 1024 * 4;
  float* cM = (float*)(ws + off); off += (size_t)64 * 1024 * 4;

  prep<<<512, 256, 0, stream>>>(Q, R, Qh, Ql, Rh, Rl, hM, cM, Nh, Nl);
  for (int t = 0; t < 512; ++t) {
    const float* xt = x + (size_t)t * 65536;
    // P1: x1 = 2*sig(h_new @ Q^T) * x_t        (A = N bands)
    mog_phase<<<64, 256, 0, stream>>>(Nh, Nl, Qh, Ql, xt, xM, Xh, Xl);
    // P2: h2 = 2*sig(x1 @ R^T) * h_prev        (A = X bands)
    mog_phase<<<64, 256, 0, stream>>>(Xh, Xl, Rh, Rl, hM, hM, Hh, Hl);
    // P3: x3 = 2*sig(h2 @ Q^T) * x1            (A = H bands)
    mog_phase<<<64, 256, 0, stream>>>(Hh, Hl, Qh, Ql, xM, xM, Xh, Xl);
    // P4: h4 = 2*sig(x3 @ R^T) * h2            (A = X bands)
    mog_phase<<<64, 256, 0, stream>>>(Xh, Xl, Rh, Rl, hM, hM, Hh, Hl);
    // P5: x5 = 2*sig(h4 @ Q^T) * x3            (A = H bands)
    mog_phase<<<64, 256, 0, stream>>>(Hh, Hl, Qh, Ql, xM, xM, Xh, Xl);
    // P6: gates + LSTM update                  (reads X,H; writes N,hM,cM)
    gate_step<<<64, 256, 0, stream>>>(Xh, Xl, Hh, Hl, Wall, ball, cM, hM,
                                      Nh, Nl, out, t);
  }
}

// Round 9
// 33681.338 us; speedup vs baseline: 47.5403x; 2.0269x over previous
//
#include <hip/hip_runtime.h>
#include <hip/hip_bf16.h>
#include <math.h>

// MogLSTM S=512, B=64, E=H=1024. R9: kernel-per-phase (graph-replayed device
// sync), all dispatches full-GPU. 7 nodes/step: 5x mog_phase (256 WGs,
// M-split x N-split), gate_gemm (256 WGs, minimal 32MB W traffic, z->ws),
// lstm_update (elementwise). Numerics identical to r8 (absmax 0.0039):
// bf16 hi+lo 4-term products, fp32 masters, accurate expf/tanhf.

using bf16   = __bf16;
using bf16x4 = __attribute__((ext_vector_type(4))) __bf16;
using bf16x8 = __attribute__((ext_vector_type(8))) __bf16;
using f32x4  = __attribute__((ext_vector_type(4))) float;

#define MFMA16(a,b,c) __builtin_amdgcn_mfma_f32_16x16x32_bf16((a),(b),(c),0,0,0)

__device__ __forceinline__ float fsig(float x) { return 1.f / (1.f + expf(-x)); }

// ---------------- prologue: Q/R hi+lo split, zero state ----------------
__global__ void prep(const float* __restrict__ Q, const float* __restrict__ R,
                     bf16* __restrict__ Qh, bf16* __restrict__ Ql,
                     bf16* __restrict__ Rh, bf16* __restrict__ Rl,
                     float* __restrict__ hM, float* __restrict__ cM,
                     bf16* __restrict__ Nh, bf16* __restrict__ Nl) {
  const long tid = (long)blockIdx.x * blockDim.x + threadIdx.x;
  const long nth = (long)gridDim.x * blockDim.x;
  for (long i = tid; i < 1024L * 1024 / 4; i += nth) {
    float4 v = ((const float4*)Q)[i];
    bf16 a0 = (bf16)v.x, a1 = (bf16)v.y, a2 = (bf16)v.z, a3 = (bf16)v.w;
    Qh[i*4+0] = a0; Qh[i*4+1] = a1; Qh[i*4+2] = a2; Qh[i*4+3] = a3;
    Ql[i*4+0] = (bf16)(v.x - (float)a0); Ql[i*4+1] = (bf16)(v.y - (float)a1);
    Ql[i*4+2] = (bf16)(v.z - (float)a2); Ql[i*4+3] = (bf16)(v.w - (float)a3);
    float4 u = ((const float4*)R)[i];
    bf16 b0 = (bf16)u.x, b1 = (bf16)u.y, b2 = (bf16)u.z, b3 = (bf16)u.w;
    Rh[i*4+0] = b0; Rh[i*4+1] = b1; Rh[i*4+2] = b2; Rh[i*4+3] = b3;
    Rl[i*4+0] = (bf16)(u.x - (float)b0); Rl[i*4+1] = (bf16)(u.y - (float)b1);
    Rl[i*4+2] = (bf16)(u.z - (float)b2); Rl[i*4+3] = (bf16)(u.w - (float)b3);
  }
  for (long i = tid; i < 64L * 1024; i += nth) {
    hM[i] = 0.f; cM[i] = 0.f; Nh[i] = (bf16)0.f; Nl[i] = (bf16)0.f;
  }
}

// ---------------- mogrifier phase ----------------
// dst = 2*sig(A @ B^T) * mult. Grid 256 WGs: mt = bid>>6 (16-row M tile),
// c = bid&63 (16-col N tile). Wave w = K-quarter (256). Fragment mappings
// carried verbatim from the r8-verified kernel.
__global__ __launch_bounds__(256) void mog_phase(
    const bf16* __restrict__ Ah, const bf16* __restrict__ Al,
    const bf16* __restrict__ Bh, const bf16* __restrict__ Bl,
    const float* __restrict__ mult, float* __restrict__ dstM,
    bf16* __restrict__ Dh, bf16* __restrict__ Dl) {
  __shared__ f32x4 red[3][64];
  const int mt = blockIdx.x >> 6, c = blockIdx.x & 63;
  const int tid = threadIdx.x, l = tid & 63, w = tid >> 6;
  const int r16 = l & 15, kg = l >> 4;
  const size_t kb = (size_t)w * 256 + kg * 8;
  const bf16* bhp = Bh + (size_t)(16 * c + r16) * 1024 + kb;
  const bf16* blp = Bl + (size_t)(16 * c + r16) * 1024 + kb;
  const bf16* ahp = Ah + (size_t)(16 * mt + r16) * 1024 + kb;
  const bf16* alp = Al + (size_t)(16 * mt + r16) * 1024 + kb;
  f32x4 acc = {};
#pragma unroll
  for (int ks = 0; ks < 8; ++ks) {
    bf16x8 bh = *(const bf16x8*)(bhp + ks * 32);
    bf16x8 bl = *(const bf16x8*)(blp + ks * 32);
    bf16x8 ah = *(const bf16x8*)(ahp + ks * 32);
    bf16x8 al = *(const bf16x8*)(alp + ks * 32);
    acc = MFMA16(al, bl, acc);   // smallest term first
    acc = MFMA16(al, bh, acc);
    acc = MFMA16(ah, bl, acc);
    acc = MFMA16(ah, bh, acc);
  }
  if (w) red[w - 1][l] = acc;
  __syncthreads();
  if (w == 0) {
#pragma unroll
    for (int kk = 0; kk < 3; ++kk) acc += red[kk][l];
    const int col = 16 * c + r16;             // C-frag: col = lane&15
#pragma unroll
    for (int q = 0; q < 4; ++q) {
      const int row = 16 * mt + kg * 4 + q;   // row = (lane>>4)*4 + reg
      const size_t idx = (size_t)row * 1024 + col;
      float v = 2.f * fsig(acc[q]) * mult[idx];
      dstM[idx] = v;
      bf16 hi = (bf16)v;
      Dh[idx] = hi;
      Dl[idx] = (bf16)(v - (float)hi);
    }
  }
}

// ---------------- gate GEMM: z = [x5,h4] @ W^T (no bias) ----------------
// Grid 256 WGs: nt = bid -> gate cols 16nt..16nt+15 (covers all 4 gates).
// M = 64 batch rows (4 m-tiles per wave-slice). Wave w = K-slice of 512:
// w<2 from X bands, w>=2 from H bands. W streamed f32, split on the fly.
__global__ __launch_bounds__(256) void gate_gemm(
    const bf16* __restrict__ Xh, const bf16* __restrict__ Xl,
    const bf16* __restrict__ Hh, const bf16* __restrict__ Hl,
    const float* __restrict__ Wf, float* __restrict__ zbuf) {
  __shared__ f32x4 red[3][4][64];
  const int nt = blockIdx.x;
  const int tid = threadIdx.x, l = tid & 63, w = tid >> 6;
  const int r16 = l & 15, kg = l >> 4;
  const bf16* Abh = (w < 2) ? Xh : Hh;
  const bf16* Abl = (w < 2) ? Xl : Hl;
  const size_t kb = (size_t)(w & 1) * 512 + kg * 8;
  const float* wp = Wf + (size_t)(nt * 16 + r16) * 2048 + (size_t)w * 512 + kg * 8;
  f32x4 acc[4] = {};
#pragma unroll
  for (int ks = 0; ks < 16; ++ks) {
    f32x4 w0 = *(const f32x4*)(wp + ks * 32);
    f32x4 w1 = *(const f32x4*)(wp + ks * 32 + 4);
    bf16x8 bh, bl;
#pragma unroll
    for (int e = 0; e < 4; ++e) {
      bf16 t0 = (bf16)w0[e]; bh[e] = t0;     bl[e] = (bf16)(w0[e] - (float)t0);
      bf16 t1 = (bf16)w1[e]; bh[4 + e] = t1; bl[4 + e] = (bf16)(w1[e] - (float)t1);
    }
#pragma unroll
    for (int m = 0; m < 4; ++m) {
      bf16x8 ah = *(const bf16x8*)(Abh + (size_t)(16 * m + r16) * 1024 + kb + ks * 32);
      bf16x8 al = *(const bf16x8*)(Abl + (size_t)(16 * m + r16) * 1024 + kb + ks * 32);
      acc[m] = MFMA16(al, bl, acc[m]);
      acc[m] = MFMA16(al, bh, acc[m]);
      acc[m] = MFMA16(ah, bl, acc[m]);
      acc[m] = MFMA16(ah, bh, acc[m]);
    }
  }
  if (w) {
#pragma unroll
    for (int m = 0; m < 4; ++m) red[w - 1][m][l] = acc[m];
  }
  __syncthreads();
  if (w == 0) {
#pragma unroll
    for (int m = 0; m < 4; ++m) {
#pragma unroll
      for (int kk = 0; kk < 3; ++kk) acc[m] += red[kk][m][l];
      const int col = 16 * nt + r16;
#pragma unroll
      for (int q = 0; q < 4; ++q) {
        const int row = 16 * m + kg * 4 + q;
        zbuf[(size_t)row * 4096 + col] = acc[m][q];
      }
    }
  }
}

// ---------------- LSTM pointwise update ----------------
// 16384 threads: thread -> (row, 4 h-cols). Reads z + cM, writes cM,hM,
// N bands, out[t] (and final h,c at t=511).
__global__ __launch_bounds__(256) void lstm_update(
    const float* __restrict__ zbuf, const float* __restrict__ ball,
    float* __restrict__ cM, float* __restrict__ hM,
    bf16* __restrict__ Nh, bf16* __restrict__ Nl,
    float* __restrict__ out, int t) {
  const int gt = blockIdx.x * 256 + threadIdx.x;   // 0..16383
  const int r = gt >> 8, c4 = (gt & 255) * 4;
  const size_t zb = (size_t)r * 4096 + c4;
  f32x4 zi = *(const f32x4*)(zbuf + zb);
  f32x4 zf = *(const f32x4*)(zbuf + zb + 1024);
  f32x4 zg = *(const f32x4*)(zbuf + zb + 2048);
  f32x4 zo = *(const f32x4*)(zbuf + zb + 3072);
  f32x4 bi = *(const f32x4*)(ball + c4);
  f32x4 bf_ = *(const f32x4*)(ball + 1024 + c4);
  f32x4 bg = *(const f32x4*)(ball + 2048 + c4);
  f32x4 bo = *(const f32x4*)(ball + 3072 + c4);
  const size_t idx = (size_t)r * 1024 + c4;
  f32x4 cc = *(const f32x4*)(cM + idx);
  f32x4 hh;
  bf16x4 nh, nl;
#pragma unroll
  for (int e = 0; e < 4; ++e) {
    float ci = cc[e];
    float nc = fsig(zf[e] + bf_[e]) * ci + fsig(zi[e] + bi[e]) * tanhf(zg[e] + bg[e]);
    float nh_ = fsig(zo[e] + bo[e]) * tanhf(nc);
    cc[e] = nc; hh[e] = nh_;
    bf16 hib = (bf16)nh_;
    nh[e] = hib;
    nl[e] = (bf16)(nh_ - (float)hib);
  }
  *(f32x4*)(cM + idx) = cc;
  *(f32x4*)(hM + idx) = hh;
  *(bf16x4*)(Nh + idx) = nh;
  *(bf16x4*)(Nl + idx) = nl;
  *(f32x4*)(out + (size_t)t * 65536 + idx) = hh;
  if (t == 511) {
    *(f32x4*)(out + (size_t)512 * 65536 + idx) = hh;
    *(f32x4*)(out + (size_t)512 * 65536 + 65536 + idx) = cc;
  }
}

extern "C" void kernel_launch(void* const* d_in, const int* in_sizes, int n_in,
                              void* d_out, int out_size, void* d_ws, size_t ws_size,
                              hipStream_t stream) {
  (void)in_sizes; (void)n_in; (void)out_size; (void)ws_size;
  const float* x    = (const float*)d_in[0];
  const float* Wall = (const float*)d_in[1];
  const float* ball = (const float*)d_in[2];
  const float* Q    = (const float*)d_in[3];
  const float* R    = (const float*)d_in[4];
  float* out = (float*)d_out;

  char* ws = (char*)d_ws;
  size_t off = 0;
  bf16* Qh = (bf16*)(ws + off); off += (size_t)1024 * 1024 * 2;   // 2 MB
  bf16* Ql = (bf16*)(ws + off); off += (size_t)1024 * 1024 * 2;
  bf16* Rh = (bf16*)(ws + off); off += (size_t)1024 * 1024 * 2;
  bf16* Rl = (bf16*)(ws + off); off += (size_t)1024 * 1024 * 2;
  bf16* Xh = (bf16*)(ws + off); off += (size_t)64 * 1024 * 2;     // 128 KB each
  bf16* Xl = (bf16*)(ws + off); off += (size_t)64 * 1024 * 2;
  bf16* Hh = (bf16*)(ws + off); off += (size_t)64 * 1024 * 2;
  bf16* Hl = (bf16*)(ws + off); off += (size_t)64 * 1024 * 2;
  bf16* Nh = (bf16*)(ws + off); off += (size_t)64 * 1024 * 2;
  bf16* Nl = (bf16*)(ws + off); off += (size_t)64 * 1024 * 2;
  float* xM = (float*)(ws + off); off += (size_t)64 * 1024 * 4;   // 256 KB each
  float* hM = (float*)(ws + off); off += (size_t)64 * 1024 * 4;
  float* cM = (float*)(ws + off); off += (size_t)64 * 1024 * 4;
  float* zbuf = (float*)(ws + off); off += (size_t)64 * 4096 * 4; // 1 MB

  prep<<<512, 256, 0, stream>>>(Q, R, Qh, Ql, Rh, Rl, hM, cM, Nh, Nl);
  for (int t = 0; t < 512; ++t) {
    const float* xt = x + (size_t)t * 65536;
    // P1: x1 = 2*sig(h_new @ Q^T) * x_t        (A = N bands)
    mog_phase<<<256, 256, 0, stream>>>(Nh, Nl, Qh, Ql, xt, xM, Xh, Xl);
    // P2: h2 = 2*sig(x1 @ R^T) * h_prev        (A = X bands)
    mog_phase<<<256, 256, 0, stream>>>(Xh, Xl, Rh, Rl, hM, hM, Hh, Hl);
    // P3: x3 = 2*sig(h2 @ Q^T) * x1            (A = H bands)
    mog_phase<<<256, 256, 0, stream>>>(Hh, Hl, Qh, Ql, xM, xM, Xh, Xl);
    // P4: h4 = 2*sig(x3 @ R^T) * h2            (A = X bands)
    mog_phase<<<256, 256, 0, stream>>>(Xh, Xl, Rh, Rl, hM, hM, Hh, Hl);
    // P5: x5 = 2*sig(h4 @ Q^T) * x3            (A = H bands)
    mog_phase<<<256, 256, 0, stream>>>(Hh, Hl, Qh, Ql, xM, xM, Xh, Xl);
    // P6a: gate GEMM -> z                      (reads X,H bands; writes zbuf)
    gate_gemm<<<256, 256, 0, stream>>>(Xh, Xl, Hh, Hl, Wall, zbuf);
    // P6b: pointwise LSTM update               (reads zbuf,cM; writes state+out)
    lstm_update<<<64, 256, 0, stream>>>(zbuf, ball, cM, hM, Nh, Nl, out, t);
  }
}

// Round 10
// 31953.226 us; speedup vs baseline: 50.1114x; 1.0541x over previous
//
#include <hip/hip_runtime.h>
#include <hip/hip_bf16.h>
#include <math.h>

// MogLSTM S=512, B=64, E=H=1024. R10: 6 nodes/step (5x mog_phase + fused
// gate4 = gate GEMM + LSTM update). gate4 packs {4 gates x 4 hcols} as the
// MFMA B-operand's 16 columns so W is still read exactly once per step and
// the pointwise LSTM update is WG-local (no extra sync node, no zbuf).
// W optionally pre-split to bf16 hi/lo (runtime ws_size check; f32
// on-the-fly fallback, both paths identical numerics). mog_phase is
// byte-identical to the r9-verified kernel. absmax target ~0.0039.

using bf16   = __bf16;
using bf16x4 = __attribute__((ext_vector_type(4))) __bf16;
using bf16x8 = __attribute__((ext_vector_type(8))) __bf16;
using f32x4  = __attribute__((ext_vector_type(4))) float;

#define MFMA16(a,b,c) __builtin_amdgcn_mfma_f32_16x16x32_bf16((a),(b),(c),0,0,0)

__device__ __forceinline__ float fsig(float x) { return 1.f / (1.f + expf(-x)); }

// ---------------- prologue: Q/R (and optionally W) hi+lo split ------------
__global__ void prep(const float* __restrict__ Q, const float* __restrict__ R,
                     const float* __restrict__ Wf,
                     bf16* __restrict__ Qh, bf16* __restrict__ Ql,
                     bf16* __restrict__ Rh, bf16* __restrict__ Rl,
                     bf16* __restrict__ Whi, bf16* __restrict__ Wlo,
                     float* __restrict__ hM, float* __restrict__ cM,
                     bf16* __restrict__ Nh, bf16* __restrict__ Nl, int wsplit) {
  const long tid = (long)blockIdx.x * blockDim.x + threadIdx.x;
  const long nth = (long)gridDim.x * blockDim.x;
  for (long i = tid; i < 1024L * 1024 / 4; i += nth) {
    float4 v = ((const float4*)Q)[i];
    bf16 a0 = (bf16)v.x, a1 = (bf16)v.y, a2 = (bf16)v.z, a3 = (bf16)v.w;
    Qh[i*4+0] = a0; Qh[i*4+1] = a1; Qh[i*4+2] = a2; Qh[i*4+3] = a3;
    Ql[i*4+0] = (bf16)(v.x - (float)a0); Ql[i*4+1] = (bf16)(v.y - (float)a1);
    Ql[i*4+2] = (bf16)(v.z - (float)a2); Ql[i*4+3] = (bf16)(v.w - (float)a3);
    float4 u = ((const float4*)R)[i];
    bf16 b0 = (bf16)u.x, b1 = (bf16)u.y, b2 = (bf16)u.z, b3 = (bf16)u.w;
    Rh[i*4+0] = b0; Rh[i*4+1] = b1; Rh[i*4+2] = b2; Rh[i*4+3] = b3;
    Rl[i*4+0] = (bf16)(u.x - (float)b0); Rl[i*4+1] = (bf16)(u.y - (float)b1);
    Rl[i*4+2] = (bf16)(u.z - (float)b2); Rl[i*4+3] = (bf16)(u.w - (float)b3);
  }
  if (wsplit) {
    for (long i = tid; i < 4096L * 2048 / 4; i += nth) {
      float4 v = ((const float4*)Wf)[i];
      bf16 a0 = (bf16)v.x, a1 = (bf16)v.y, a2 = (bf16)v.z, a3 = (bf16)v.w;
      Whi[i*4+0] = a0; Whi[i*4+1] = a1; Whi[i*4+2] = a2; Whi[i*4+3] = a3;
      Wlo[i*4+0] = (bf16)(v.x - (float)a0); Wlo[i*4+1] = (bf16)(v.y - (float)a1);
      Wlo[i*4+2] = (bf16)(v.z - (float)a2); Wlo[i*4+3] = (bf16)(v.w - (float)a3);
    }
  }
  for (long i = tid; i < 64L * 1024; i += nth) {
    hM[i] = 0.f; cM[i] = 0.f; Nh[i] = (bf16)0.f; Nl[i] = (bf16)0.f;
  }
}

// ---------------- mogrifier phase (byte-identical to r9-verified) ---------
__global__ __launch_bounds__(256) void mog_phase(
    const bf16* __restrict__ Ah, const bf16* __restrict__ Al,
    const bf16* __restrict__ Bh, const bf16* __restrict__ Bl,
    const float* __restrict__ mult, float* __restrict__ dstM,
    bf16* __restrict__ Dh, bf16* __restrict__ Dl) {
  __shared__ f32x4 red[3][64];
  const int mt = blockIdx.x >> 6, c = blockIdx.x & 63;
  const int tid = threadIdx.x, l = tid & 63, w = tid >> 6;
  const int r16 = l & 15, kg = l >> 4;
  const size_t kb = (size_t)w * 256 + kg * 8;
  const bf16* bhp = Bh + (size_t)(16 * c + r16) * 1024 + kb;
  const bf16* blp = Bl + (size_t)(16 * c + r16) * 1024 + kb;
  const bf16* ahp = Ah + (size_t)(16 * mt + r16) * 1024 + kb;
  const bf16* alp = Al + (size_t)(16 * mt + r16) * 1024 + kb;
  f32x4 acc = {};
#pragma unroll
  for (int ks = 0; ks < 8; ++ks) {
    bf16x8 bh = *(const bf16x8*)(bhp + ks * 32);
    bf16x8 bl = *(const bf16x8*)(blp + ks * 32);
    bf16x8 ah = *(const bf16x8*)(ahp + ks * 32);
    bf16x8 al = *(const bf16x8*)(alp + ks * 32);
    acc = MFMA16(al, bl, acc);
    acc = MFMA16(al, bh, acc);
    acc = MFMA16(ah, bl, acc);
    acc = MFMA16(ah, bh, acc);
  }
  if (w) red[w - 1][l] = acc;
  __syncthreads();
  if (w == 0) {
#pragma unroll
    for (int kk = 0; kk < 3; ++kk) acc += red[kk][l];
    const int col = 16 * c + r16;
#pragma unroll
    for (int q = 0; q < 4; ++q) {
      const int row = 16 * mt + kg * 4 + q;
      const size_t idx = (size_t)row * 1024 + col;
      float v = 2.f * fsig(acc[q]) * mult[idx];
      dstM[idx] = v;
      bf16 hi = (bf16)v;
      Dh[idx] = hi;
      Dl[idx] = (bf16)(v - (float)hi);
    }
  }
}

// ---------------- fused gate GEMM + LSTM update ----------------
// Grid 256 WGs: WG g owns hcols 4g..4g+3 for ALL 4 gates. B-operand col
// r16 -> W row (r16>>2)*1024 + 4g + (r16&3); W read exactly once per step.
// Wave w = K-slice of 512 (w<2: X bands, w>=2: H bands). Epilogue: all-waves
// LDS partials; thread t -> (row=t>>2, hc=t&3) does the LSTM update.
template <int WSPLIT>
__global__ __launch_bounds__(256) void gate4(
    const bf16* __restrict__ Xh, const bf16* __restrict__ Xl,
    const bf16* __restrict__ Hh, const bf16* __restrict__ Hl,
    const float* __restrict__ Wf, const bf16* __restrict__ Whi,
    const bf16* __restrict__ Wlo, const float* __restrict__ ball,
    float* __restrict__ cM, float* __restrict__ hM,
    bf16* __restrict__ Nh, bf16* __restrict__ Nl,
    float* __restrict__ out, int t) {
  __shared__ f32x4 red[4][4][64];   // [wave][m][lane] = 16 KB
  const int g = blockIdx.x;
  const int tid = threadIdx.x, l = tid & 63, w = tid >> 6;
  const int r16 = l & 15, kg = l >> 4;
  const bf16* Abh = (w < 2) ? Xh : Hh;
  const bf16* Abl = (w < 2) ? Xl : Hl;
  const size_t kb = (size_t)(w & 1) * 512 + kg * 8;
  const size_t wrow = (size_t)(r16 >> 2) * 1024 + 4 * g + (r16 & 3);
  const float* wp  = Wf  + wrow * 2048 + (size_t)w * 512 + kg * 8;
  const bf16*  whp = Whi + wrow * 2048 + (size_t)w * 512 + kg * 8;
  const bf16*  wlp = Wlo + wrow * 2048 + (size_t)w * 512 + kg * 8;
  f32x4 acc[4] = {};
#pragma unroll
  for (int ks = 0; ks < 16; ++ks) {
    bf16x8 bh, bl;
    if (WSPLIT) {
      bh = *(const bf16x8*)(whp + ks * 32);
      bl = *(const bf16x8*)(wlp + ks * 32);
    } else {
      f32x4 w0 = *(const f32x4*)(wp + ks * 32);
      f32x4 w1 = *(const f32x4*)(wp + ks * 32 + 4);
#pragma unroll
      for (int e = 0; e < 4; ++e) {
        bf16 t0 = (bf16)w0[e]; bh[e] = t0;     bl[e] = (bf16)(w0[e] - (float)t0);
        bf16 t1 = (bf16)w1[e]; bh[4 + e] = t1; bl[4 + e] = (bf16)(w1[e] - (float)t1);
      }
    }
#pragma unroll
    for (int m = 0; m < 4; ++m) {
      bf16x8 ah = *(const bf16x8*)(Abh + (size_t)(16 * m + r16) * 1024 + kb + ks * 32);
      bf16x8 al = *(const bf16x8*)(Abl + (size_t)(16 * m + r16) * 1024 + kb + ks * 32);
      acc[m] = MFMA16(al, bl, acc[m]);
      acc[m] = MFMA16(al, bh, acc[m]);
      acc[m] = MFMA16(ah, bl, acc[m]);
      acc[m] = MFMA16(ah, bh, acc[m]);
    }
  }
#pragma unroll
  for (int m = 0; m < 4; ++m) red[w][m][l] = acc[m];
  __syncthreads();
  // epilogue: thread t -> row = t>>2 (0..63), hc = t&3
  {
    const int row = tid >> 2, hc = tid & 3;
    const int m = row >> 4, rem = row & 15;
    const int kgq = rem >> 2, q = rem & 3;
    const int hcg = 4 * g + hc;
    float z[4];
#pragma unroll
    for (int gg = 0; gg < 4; ++gg) {
      const int lane = kgq * 16 + gg * 4 + hc;
      float s = red[0][m][lane][q];
#pragma unroll
      for (int kk = 1; kk < 4; ++kk) s += red[kk][m][lane][q];
      z[gg] = s;
    }
    const float zi = z[0] + ball[hcg];
    const float zf = z[1] + ball[1024 + hcg];
    const float zg = z[2] + ball[2048 + hcg];
    const float zo = z[3] + ball[3072 + hcg];
    const size_t idx = (size_t)row * 1024 + hcg;
    const float cc = fsig(zf) * cM[idx] + fsig(zi) * tanhf(zg);
    const float hh = fsig(zo) * tanhf(cc);
    cM[idx] = cc;
    hM[idx] = hh;
    bf16 hib = (bf16)hh;
    Nh[idx] = hib;
    Nl[idx] = (bf16)(hh - (float)hib);
    out[(size_t)t * 65536 + idx] = hh;
    if (t == 511) {
      out[(size_t)512 * 65536 + idx] = hh;
      out[(size_t)512 * 65536 + 65536 + idx] = cc;
    }
  }
}

extern "C" void kernel_launch(void* const* d_in, const int* in_sizes, int n_in,
                              void* d_out, int out_size, void* d_ws, size_t ws_size,
                              hipStream_t stream) {
  (void)in_sizes; (void)n_in; (void)out_size;
  const float* x    = (const float*)d_in[0];
  const float* Wall = (const float*)d_in[1];
  const float* ball = (const float*)d_in[2];
  const float* Q    = (const float*)d_in[3];
  const float* R    = (const float*)d_in[4];
  float* out = (float*)d_out;

  char* ws = (char*)d_ws;
  size_t off = 0;
  bf16* Qh = (bf16*)(ws + off); off += (size_t)1024 * 1024 * 2;   // 2 MB
  bf16* Ql = (bf16*)(ws + off); off += (size_t)1024 * 1024 * 2;
  bf16* Rh = (bf16*)(ws + off); off += (size_t)1024 * 1024 * 2;
  bf16* Rl = (bf16*)(ws + off); off += (size_t)1024 * 1024 * 2;
  bf16* Xh = (bf16*)(ws + off); off += (size_t)64 * 1024 * 2;     // 128 KB each
  bf16* Xl = (bf16*)(ws + off); off += (size_t)64 * 1024 * 2;
  bf16* Hh = (bf16*)(ws + off); off += (size_t)64 * 1024 * 2;
  bf16* Hl = (bf16*)(ws + off); off += (size_t)64 * 1024 * 2;
  bf16* Nh = (bf16*)(ws + off); off += (size_t)64 * 1024 * 2;
  bf16* Nl = (bf16*)(ws + off); off += (size_t)64 * 1024 * 2;
  float* xM = (float*)(ws + off); off += (size_t)64 * 1024 * 4;   // 256 KB each
  float* hM = (float*)(ws + off); off += (size_t)64 * 1024 * 4;
  float* cM = (float*)(ws + off); off += (size_t)64 * 1024 * 4;
  // optional W hi/lo bands (2 x 16.78 MB)
  bf16* Whi = (bf16*)(ws + off);
  bf16* Wlo = (bf16*)(ws + off + (size_t)4096 * 2048 * 2);
  const int wsplit = (ws_size >= off + (size_t)2 * 4096 * 2048 * 2) ? 1 : 0;

  prep<<<512, 256, 0, stream>>>(Q, R, Wall, Qh, Ql, Rh, Rl, Whi, Wlo,
                                hM, cM, Nh, Nl, wsplit);
  for (int t = 0; t < 512; ++t) {
    const float* xt = x + (size_t)t * 65536;
    mog_phase<<<256, 256, 0, stream>>>(Nh, Nl, Qh, Ql, xt, xM, Xh, Xl);
    mog_phase<<<256, 256, 0, stream>>>(Xh, Xl, Rh, Rl, hM, hM, Hh, Hl);
    mog_phase<<<256, 256, 0, stream>>>(Hh, Hl, Qh, Ql, xM, xM, Xh, Xl);
    mog_phase<<<256, 256, 0, stream>>>(Xh, Xl, Rh, Rl, hM, hM, Hh, Hl);
    mog_phase<<<256, 256, 0, stream>>>(Hh, Hl, Qh, Ql, xM, xM, Xh, Xl);
    if (wsplit)
      gate4<1><<<256, 256, 0, stream>>>(Xh, Xl, Hh, Hl, Wall, Whi, Wlo, ball,
                                        cM, hM, Nh, Nl, out, t);
    else
      gate4<0><<<256, 256, 0, stream>>>(Xh, Xl, Hh, Hl, Wall, Whi, Wlo, ball,
                                        cM, hM, Nh, Nl, out, t);
  }
}

// Round 11
// 27955.167 us; speedup vs baseline: 57.2782x; 1.1430x over previous
//
#include <hip/hip_runtime.h>
#include <hip/hip_bf16.h>
#include <math.h>

// MogLSTM S=512, B=64, E=H=1024. R11: same 6-node/step graph as r10
// (5x mog_phase + fused gate4), but 512-thread blocks (2 waves/SIMD) and
// 8-way K-split per WG to hide the cold-L2 (post-node-boundary) L3 latency.
// Numerics identical to r8-r10 (absmax 0.0039): bf16 hi+lo 4-term products,
// fp32 masters, accurate expf/tanhf. Only the fp32 partial-sum grouping
// changes (K=128/256 per wave instead of 256/512).

using bf16   = __bf16;
using bf16x4 = __attribute__((ext_vector_type(4))) __bf16;
using bf16x8 = __attribute__((ext_vector_type(8))) __bf16;
using f32x4  = __attribute__((ext_vector_type(4))) float;

#define MFMA16(a,b,c) __builtin_amdgcn_mfma_f32_16x16x32_bf16((a),(b),(c),0,0,0)

__device__ __forceinline__ float fsig(float x) { return 1.f / (1.f + expf(-x)); }

// ---------------- prologue: Q/R (and optionally W) hi+lo split ------------
__global__ void prep(const float* __restrict__ Q, const float* __restrict__ R,
                     const float* __restrict__ Wf,
                     bf16* __restrict__ Qh, bf16* __restrict__ Ql,
                     bf16* __restrict__ Rh, bf16* __restrict__ Rl,
                     bf16* __restrict__ Whi, bf16* __restrict__ Wlo,
                     float* __restrict__ hM, float* __restrict__ cM,
                     bf16* __restrict__ Nh, bf16* __restrict__ Nl, int wsplit) {
  const long tid = (long)blockIdx.x * blockDim.x + threadIdx.x;
  const long nth = (long)gridDim.x * blockDim.x;
  for (long i = tid; i < 1024L * 1024 / 4; i += nth) {
    float4 v = ((const float4*)Q)[i];
    bf16 a0 = (bf16)v.x, a1 = (bf16)v.y, a2 = (bf16)v.z, a3 = (bf16)v.w;
    Qh[i*4+0] = a0; Qh[i*4+1] = a1; Qh[i*4+2] = a2; Qh[i*4+3] = a3;
    Ql[i*4+0] = (bf16)(v.x - (float)a0); Ql[i*4+1] = (bf16)(v.y - (float)a1);
    Ql[i*4+2] = (bf16)(v.z - (float)a2); Ql[i*4+3] = (bf16)(v.w - (float)a3);
    float4 u = ((const float4*)R)[i];
    bf16 b0 = (bf16)u.x, b1 = (bf16)u.y, b2 = (bf16)u.z, b3 = (bf16)u.w;
    Rh[i*4+0] = b0; Rh[i*4+1] = b1; Rh[i*4+2] = b2; Rh[i*4+3] = b3;
    Rl[i*4+0] = (bf16)(u.x - (float)b0); Rl[i*4+1] = (bf16)(u.y - (float)b1);
    Rl[i*4+2] = (bf16)(u.z - (float)b2); Rl[i*4+3] = (bf16)(u.w - (float)b3);
  }
  if (wsplit) {
    for (long i = tid; i < 4096L * 2048 / 4; i += nth) {
      float4 v = ((const float4*)Wf)[i];
      bf16 a0 = (bf16)v.x, a1 = (bf16)v.y, a2 = (bf16)v.z, a3 = (bf16)v.w;
      Whi[i*4+0] = a0; Whi[i*4+1] = a1; Whi[i*4+2] = a2; Whi[i*4+3] = a3;
      Wlo[i*4+0] = (bf16)(v.x - (float)a0); Wlo[i*4+1] = (bf16)(v.y - (float)a1);
      Wlo[i*4+2] = (bf16)(v.z - (float)a2); Wlo[i*4+3] = (bf16)(v.w - (float)a3);
    }
  }
  for (long i = tid; i < 64L * 1024; i += nth) {
    hM[i] = 0.f; cM[i] = 0.f; Nh[i] = (bf16)0.f; Nl[i] = (bf16)0.f;
  }
}

// ---------------- mogrifier phase ----------------
// dst = 2*sig(A @ B^T) * mult. Grid 256 WGs x 512 thr. mt = bid>>6, c=bid&63.
// Wave w (0..7) = K-slice of 128 (4 ksteps). Fragment mappings as verified.
__global__ __launch_bounds__(512) void mog_phase(
    const bf16* __restrict__ Ah, const bf16* __restrict__ Al,
    const bf16* __restrict__ Bh, const bf16* __restrict__ Bl,
    const float* __restrict__ mult, float* __restrict__ dstM,
    bf16* __restrict__ Dh, bf16* __restrict__ Dl) {
  __shared__ f32x4 red[7][64];
  const int mt = blockIdx.x >> 6, c = blockIdx.x & 63;
  const int tid = threadIdx.x, l = tid & 63, w = tid >> 6;
  const int r16 = l & 15, kg = l >> 4;
  const size_t kb = (size_t)w * 128 + kg * 8;
  const bf16* bhp = Bh + (size_t)(16 * c + r16) * 1024 + kb;
  const bf16* blp = Bl + (size_t)(16 * c + r16) * 1024 + kb;
  const bf16* ahp = Ah + (size_t)(16 * mt + r16) * 1024 + kb;
  const bf16* alp = Al + (size_t)(16 * mt + r16) * 1024 + kb;
  f32x4 acc = {};
#pragma unroll
  for (int ks = 0; ks < 4; ++ks) {
    bf16x8 bh = *(const bf16x8*)(bhp + ks * 32);
    bf16x8 bl = *(const bf16x8*)(blp + ks * 32);
    bf16x8 ah = *(const bf16x8*)(ahp + ks * 32);
    bf16x8 al = *(const bf16x8*)(alp + ks * 32);
    acc = MFMA16(al, bl, acc);
    acc = MFMA16(al, bh, acc);
    acc = MFMA16(ah, bl, acc);
    acc = MFMA16(ah, bh, acc);
  }
  if (w) red[w - 1][l] = acc;
  __syncthreads();
  if (w == 0) {
#pragma unroll
    for (int kk = 0; kk < 7; ++kk) acc += red[kk][l];
    const int col = 16 * c + r16;
#pragma unroll
    for (int q = 0; q < 4; ++q) {
      const int row = 16 * mt + kg * 4 + q;
      const size_t idx = (size_t)row * 1024 + col;
      float v = 2.f * fsig(acc[q]) * mult[idx];
      dstM[idx] = v;
      bf16 hi = (bf16)v;
      Dh[idx] = hi;
      Dl[idx] = (bf16)(v - (float)hi);
    }
  }
}

// ---------------- fused gate GEMM + LSTM update ----------------
// Grid 256 WGs x 512 thr: WG g owns hcols 4g..4g+3 for ALL 4 gates (same
// B-packing as r10: col r16 -> W row (r16>>2)*1024 + 4g + (r16&3)).
// Wave w (0..7) = K-slice of 256: band = w>>2 (0:X, 1:H), kb=(w&3)*256.
template <int WSPLIT>
__global__ __launch_bounds__(512) void gate4(
    const bf16* __restrict__ Xh, const bf16* __restrict__ Xl,
    const bf16* __restrict__ Hh, const bf16* __restrict__ Hl,
    const float* __restrict__ Wf, const bf16* __restrict__ Whi,
    const bf16* __restrict__ Wlo, const float* __restrict__ ball,
    float* __restrict__ cM, float* __restrict__ hM,
    bf16* __restrict__ Nh, bf16* __restrict__ Nl,
    float* __restrict__ out, int t) {
  __shared__ f32x4 red[8][4][64];   // 32 KB
  const int g = blockIdx.x;
  const int tid = threadIdx.x, l = tid & 63, w = tid >> 6;
  const int r16 = l & 15, kg = l >> 4;
  const bf16* Abh = (w < 4) ? Xh : Hh;
  const bf16* Abl = (w < 4) ? Xl : Hl;
  const size_t kb = (size_t)(w & 3) * 256 + kg * 8;
  const size_t wrow = (size_t)(r16 >> 2) * 1024 + 4 * g + (r16 & 3);
  const float* wp  = Wf  + wrow * 2048 + (size_t)w * 256 + kg * 8;
  const bf16*  whp = Whi + wrow * 2048 + (size_t)w * 256 + kg * 8;
  const bf16*  wlp = Wlo + wrow * 2048 + (size_t)w * 256 + kg * 8;
  f32x4 acc[4] = {};
#pragma unroll
  for (int ks = 0; ks < 8; ++ks) {
    bf16x8 bh, bl;
    if (WSPLIT) {
      bh = *(const bf16x8*)(whp + ks * 32);
      bl = *(const bf16x8*)(wlp + ks * 32);
    } else {
      f32x4 w0 = *(const f32x4*)(wp + ks * 32);
      f32x4 w1 = *(const f32x4*)(wp + ks * 32 + 4);
#pragma unroll
      for (int e = 0; e < 4; ++e) {
        bf16 t0 = (bf16)w0[e]; bh[e] = t0;     bl[e] = (bf16)(w0[e] - (float)t0);
        bf16 t1 = (bf16)w1[e]; bh[4 + e] = t1; bl[4 + e] = (bf16)(w1[e] - (float)t1);
      }
    }
#pragma unroll
    for (int m = 0; m < 4; ++m) {
      bf16x8 ah = *(const bf16x8*)(Abh + (size_t)(16 * m + r16) * 1024 + kb + ks * 32);
      bf16x8 al = *(const bf16x8*)(Abl + (size_t)(16 * m + r16) * 1024 + kb + ks * 32);
      acc[m] = MFMA16(al, bl, acc[m]);
      acc[m] = MFMA16(al, bh, acc[m]);
      acc[m] = MFMA16(ah, bl, acc[m]);
      acc[m] = MFMA16(ah, bh, acc[m]);
    }
  }
#pragma unroll
  for (int m = 0; m < 4; ++m) red[w][m][l] = acc[m];
  __syncthreads();
  // epilogue: threads 0..255 -> row = tid>>2 (0..63), hc = tid&3
  if (tid < 256) {
    const int row = tid >> 2, hc = tid & 3;
    const int m = row >> 4, rem = row & 15;
    const int kgq = rem >> 2, q = rem & 3;
    const int hcg = 4 * g + hc;
    float z[4];
#pragma unroll
    for (int gg = 0; gg < 4; ++gg) {
      const int lane = kgq * 16 + gg * 4 + hc;
      float s = red[0][m][lane][q];
#pragma unroll
      for (int kk = 1; kk < 8; ++kk) s += red[kk][m][lane][q];
      z[gg] = s;
    }
    const float zi = z[0] + ball[hcg];
    const float zf = z[1] + ball[1024 + hcg];
    const float zg = z[2] + ball[2048 + hcg];
    const float zo = z[3] + ball[3072 + hcg];
    const size_t idx = (size_t)row * 1024 + hcg;
    const float cc = fsig(zf) * cM[idx] + fsig(zi) * tanhf(zg);
    const float hh = fsig(zo) * tanhf(cc);
    cM[idx] = cc;
    hM[idx] = hh;
    bf16 hib = (bf16)hh;
    Nh[idx] = hib;
    Nl[idx] = (bf16)(hh - (float)hib);
    out[(size_t)t * 65536 + idx] = hh;
    if (t == 511) {
      out[(size_t)512 * 65536 + idx] = hh;
      out[(size_t)512 * 65536 + 65536 + idx] = cc;
    }
  }
}

extern "C" void kernel_launch(void* const* d_in, const int* in_sizes, int n_in,
                              void* d_out, int out_size, void* d_ws, size_t ws_size,
                              hipStream_t stream) {
  (void)in_sizes; (void)n_in; (void)out_size;
  const float* x    = (const float*)d_in[0];
  const float* Wall = (const float*)d_in[1];
  const float* ball = (const float*)d_in[2];
  const float* Q    = (const float*)d_in[3];
  const float* R    = (const float*)d_in[4];
  float* out = (float*)d_out;

  char* ws = (char*)d_ws;
  size_t off = 0;
  bf16* Qh = (bf16*)(ws + off); off += (size_t)1024 * 1024 * 2;   // 2 MB
  bf16* Ql = (bf16*)(ws + off); off += (size_t)1024 * 1024 * 2;
  bf16* Rh = (bf16*)(ws + off); off += (size_t)1024 * 1024 * 2;
  bf16* Rl = (bf16*)(ws + off); off += (size_t)1024 * 1024 * 2;
  bf16* Xh = (bf16*)(ws + off); off += (size_t)64 * 1024 * 2;     // 128 KB each
  bf16* Xl = (bf16*)(ws + off); off += (size_t)64 * 1024 * 2;
  bf16* Hh = (bf16*)(ws + off); off += (size_t)64 * 1024 * 2;
  bf16* Hl = (bf16*)(ws + off); off += (size_t)64 * 1024 * 2;
  bf16* Nh = (bf16*)(ws + off); off += (size_t)64 * 1024 * 2;
  bf16* Nl = (bf16*)(ws + off); off += (size_t)64 * 1024 * 2;
  float* xM = (float*)(ws + off); off += (size_t)64 * 1024 * 4;   // 256 KB each
  float* hM = (float*)(ws + off); off += (size_t)64 * 1024 * 4;
  float* cM = (float*)(ws + off); off += (size_t)64 * 1024 * 4;
  // optional W hi/lo bands (2 x 16.78 MB)
  bf16* Whi = (bf16*)(ws + off);
  bf16* Wlo = (bf16*)(ws + off + (size_t)4096 * 2048 * 2);
  const int wsplit = (ws_size >= off + (size_t)2 * 4096 * 2048 * 2) ? 1 : 0;

  prep<<<512, 256, 0, stream>>>(Q, R, Wall, Qh, Ql, Rh, Rl, Whi, Wlo,
                                hM, cM, Nh, Nl, wsplit);
  for (int t = 0; t < 512; ++t) {
    const float* xt = x + (size_t)t * 65536;
    mog_phase<<<256, 512, 0, stream>>>(Nh, Nl, Qh, Ql, xt, xM, Xh, Xl);
    mog_phase<<<256, 512, 0, stream>>>(Xh, Xl, Rh, Rl, hM, hM, Hh, Hl);
    mog_phase<<<256, 512, 0, stream>>>(Hh, Hl, Qh, Ql, xM, xM, Xh, Xl);
    mog_phase<<<256, 512, 0, stream>>>(Xh, Xl, Rh, Rl, hM, hM, Hh, Hl);
    mog_phase<<<256, 512, 0, stream>>>(Hh, Hl, Qh, Ql, xM, xM, Xh, Xl);
    if (wsplit)
      gate4<1><<<256, 512, 0, stream>>>(Xh, Xl, Hh, Hl, Wall, Whi, Wlo, ball,
                                        cM, hM, Nh, Nl, out, t);
    else
      gate4<0><<<256, 512, 0, stream>>>(Xh, Xl, Hh, Hl, Wall, Whi, Wlo, ball,
                                        cM, hM, Nh, Nl, out, t);
  }
}